// Round 3
// baseline (1121.384 us; speedup 1.0000x reference)
//
#include <hip/hip_runtime.h>
#include <math.h>

// DCGRU cell, N=4096, B=32, U=64, F=66, M=5, 2 supports.
// R3: [f][b]-major bf16 x-matrices, 8 f-panels per row with panel==XCD pinning
// (blockIdx.x & 7) so SpMM gathers hit the 4MB per-XCD L2; wave-uniform CSR in
// SGPRs (scalar loads); non-temporal z/output streams. MFMA gate/cand kept,
// staging transposed.

#define NN 4096
#define BB 32
#define UU 64
#define FF 66
#define MM 5
#define CC (BB*FF)     // 2112 elements per x row (4224 B bf16)
#define CAP 128        // max nnz/row (mean ~41)
#define KPAD 360       // lx row stride in bf16 (16B-aligned: 720 B)
#define KSTEPS 11      // 11*32 = 352 >= 330

typedef unsigned short u16;
typedef __attribute__((ext_vector_type(8))) short short8;
typedef __attribute__((ext_vector_type(4))) float float4v;

__device__ __forceinline__ u16 f2bf(float f) {
  unsigned u = __float_as_uint(f);
  u += 0x7FFFu + ((u >> 16) & 1u);   // RNE
  return (u16)(u >> 16);
}
__device__ __forceinline__ unsigned pack2(float lo, float hi) {
  return (unsigned)f2bf(lo) | ((unsigned)f2bf(hi) << 16);
}
__device__ __forceinline__ float bflo(unsigned d) { return __uint_as_float(d << 16); }
__device__ __forceinline__ float bfhi(unsigned d) { return __uint_as_float(d & 0xFFFF0000u); }

__device__ __forceinline__ float sigmoidf_(float x) {
  return 1.0f / (1.0f + __expf(-x));
}
__device__ __forceinline__ float tanhf_(float x) {
  x = fminf(fmaxf(x, -15.f), 15.f);
  float e = __expf(2.f * x);
  return (e - 1.f) / (e + 1.f);
}

// ---------------- CSR extraction: one wave per row, order-preserving ---------
__global__ __launch_bounds__(256) void extract_csr(
    const float* __restrict__ S0, const float* __restrict__ S1,
    int* __restrict__ cols, float* __restrict__ vals, int* __restrict__ nnz) {
  int wave = threadIdx.x >> 6;
  int lane = threadIdx.x & 63;
  int row  = blockIdx.x * 4 + wave;
  int sup  = blockIdx.y;
  const float* srow = (sup ? S1 : S0) + (size_t)row * NN;
  int*   crow = cols + ((size_t)sup * NN + row) * CAP;
  float* vrow = vals + ((size_t)sup * NN + row) * CAP;
  int base = 0;
  for (int j0 = 0; j0 < NN; j0 += 64) {
    float v = srow[j0 + lane];
    unsigned long long mask = __ballot(v != 0.0f);
    if (v != 0.0f) {
      int pos = base + __popcll(mask & ((1ull << lane) - 1ull));
      if (pos < CAP) { crow[pos] = j0 + lane; vrow[pos] = v; }
    }
    base += __popcll(mask);
  }
  if (lane == 0) nnz[sup * NN + row] = (base < CAP) ? base : CAP;
}

// ---------------- weight prep: W -> Wt[o][k=m*66+f] bf16, zero-pad to KPAD ---
__global__ __launch_bounds__(256) void prep_w(
    const float* __restrict__ W, const float* __restrict__ W2,
    u16* __restrict__ Wt, u16* __restrict__ W2t) {
  int idx = blockIdx.x * 256 + threadIdx.x;
  if (idx < 128 * KPAD) {
    int o = idx / KPAD, k = idx - o * KPAD;
    float v = 0.f;
    if (k < 330) { int m = k / FF, f = k - m * FF; v = W[((size_t)f * MM + m) * 128 + o]; }
    Wt[(size_t)o * KPAD + k] = f2bf(v);
  } else if (idx < 192 * KPAD) {
    int i = idx - 128 * KPAD;
    int o = i / KPAD, k = i - o * KPAD;
    float v = 0.f;
    if (k < 330) { int m = k / FF, f = k - m * FF; v = W2[((size_t)f * MM + m) * UU + o]; }
    W2t[(size_t)o * KPAD + k] = f2bf(v);
  }
}

// ---------------- build x0[n][f*32+b] bf16 -----------------------------------
__global__ __launch_bounds__(256) void build_x0(
    const float* __restrict__ inp, const float* __restrict__ hx,
    u16* __restrict__ x0) {
  int n = blockIdx.x;
  unsigned* xr = (unsigned*)(x0 + (size_t)n * CC);
  for (int d = threadIdx.x; d < CC / 2; d += 256) {   // 1056 dwords
    int f = d >> 4, b = (d & 15) * 2;
    float lo, hi;
    if (f < 2) {
      lo = inp[(size_t)b * (NN * 2) + n * 2 + f];
      hi = inp[(size_t)(b + 1) * (NN * 2) + n * 2 + f];
    } else {
      lo = hx[(size_t)b * (NN * UU) + n * UU + f - 2];
      hi = hx[(size_t)(b + 1) * (NN * UU) + n * UU + f - 2];
    }
    xr[d] = pack2(lo, hi);
  }
}

// ---------------- SpMM with f-panels, panel==XCD pinning ---------------------
// grid (8192, npair): blockIdx.x = rowgrp*8 + panel; 4 waves = 4 rows/block.
// out[row, panel] = alpha * sum_k val * xs[col, panel]  (+ beta * z[row, panel])
__global__ __launch_bounds__(256) void spmm_panel(
    const int* __restrict__ cols, const float* __restrict__ vals,
    const int* __restrict__ nnz,
    const u16* xA, const u16* xB, const u16* z,
    float alpha, float beta, int sup_base,
    u16* __restrict__ outA, u16* __restrict__ outB) {
  int panel = blockIdx.x & 7;
  int rowg  = blockIdx.x >> 3;
  int wv    = threadIdx.x >> 6;
  int lane  = threadIdx.x & 63;
  int row   = __builtin_amdgcn_readfirstlane(rowg * 4 + wv);
  const u16* xs = blockIdx.y ? xB : xA;
  u16* out = blockIdx.y ? outB : outA;
  int supc = sup_base + blockIdx.y;
  int fs  = panel ? (8 * panel + 2) : 0;       // panel f-start
  size_t pofs = (size_t)fs * BB;               // element offset of panel
  int srow = supc * NN + row;
  const int*   crow = cols + (size_t)srow * CAP;
  const float* vrow = vals + (size_t)srow * CAP;
  int cnt = nnz[srow];
  const u16* xsp = xs + pofs;
  bool ext = (panel == 0) && (lane < 16);      // panel0 has 80 uint2 chunks
  float a0[4] = {0.f, 0.f, 0.f, 0.f};
  float a1[4] = {0.f, 0.f, 0.f, 0.f};
  int lofs = lane * 4;                         // element offset within panel
#pragma unroll 2
  for (int k = 0; k < cnt; ++k) {
    int c = crow[k];                           // wave-uniform -> s_load
    float v = vrow[k];
    const u16* xr = xsp + (size_t)c * CC;
    uint2 q = *(const uint2*)(xr + lofs);
    a0[0] = fmaf(v, bflo(q.x), a0[0]);
    a0[1] = fmaf(v, bfhi(q.x), a0[1]);
    a0[2] = fmaf(v, bflo(q.y), a0[2]);
    a0[3] = fmaf(v, bfhi(q.y), a0[3]);
    if (ext) {
      uint2 q2 = *(const uint2*)(xr + 256 + lofs);
      a1[0] = fmaf(v, bflo(q2.x), a1[0]);
      a1[1] = fmaf(v, bfhi(q2.x), a1[1]);
      a1[2] = fmaf(v, bflo(q2.y), a1[2]);
      a1[3] = fmaf(v, bfhi(q2.y), a1[3]);
    }
  }
  size_t obase = (size_t)row * CC + pofs + lofs;
  float r0 = alpha * a0[0], r1 = alpha * a0[1];
  float r2 = alpha * a0[2], r3 = alpha * a0[3];
  if (z) {
    unsigned z0 = __builtin_nontemporal_load((const unsigned*)(z + obase));
    unsigned z1 = __builtin_nontemporal_load((const unsigned*)(z + obase) + 1);
    r0 += beta * bflo(z0); r1 += beta * bfhi(z0);
    r2 += beta * bflo(z1); r3 += beta * bfhi(z1);
  }
  __builtin_nontemporal_store(pack2(r0, r1), (unsigned*)(out + obase));
  __builtin_nontemporal_store(pack2(r2, r3), (unsigned*)(out + obase) + 1);
  if (ext) {
    float s0 = alpha * a1[0], s1 = alpha * a1[1];
    float s2 = alpha * a1[2], s3 = alpha * a1[3];
    if (z) {
      unsigned z0 = __builtin_nontemporal_load((const unsigned*)(z + obase + 256));
      unsigned z1 = __builtin_nontemporal_load((const unsigned*)(z + obase + 256) + 1);
      s0 += beta * bflo(z0); s1 += beta * bfhi(z0);
      s2 += beta * bflo(z1); s3 += beta * bfhi(z1);
    }
    __builtin_nontemporal_store(pack2(s0, s1), (unsigned*)(out + obase + 256));
    __builtin_nontemporal_store(pack2(s2, s3), (unsigned*)(out + obase + 256) + 1);
  }
}

// ---------------- staging: 5 mats [f][b] -> lx[b][k=m*66+f], k-pad zeroed ----
__device__ __forceinline__ void stage_mats_t(
    u16* lx, int n,
    const u16* m0, const u16* m1, const u16* m2, const u16* m3, const u16* m4) {
  unsigned* lxd = (unsigned*)lx;
#pragma unroll
  for (int m = 0; m < MM; ++m) {
    const u16* src = (m == 0) ? m0 : (m == 1) ? m1 : (m == 2) ? m2 : (m == 3) ? m3 : m4;
    const unsigned* s = (const unsigned*)(src + (size_t)n * CC);
    // 528 dword-pairs: j -> f=2*(j>>4), bpair=j&15; combine f,f+1 into dwords
    for (int j = threadIdx.x; j < 528; j += 256) {
      int f = (j >> 4) * 2, bp = j & 15;
      unsigned v0 = s[(f) * 16 + bp];        // (f,   b), (f,   b+1)
      unsigned v1 = s[(f + 1) * 16 + bp];    // (f+1, b), (f+1, b+1)
      int b = bp * 2;
      lxd[b * (KPAD / 2) + m * 33 + (f >> 1)]       = (v0 & 0xFFFFu) | (v1 << 16);
      lxd[(b + 1) * (KPAD / 2) + m * 33 + (f >> 1)] = (v0 >> 16) | (v1 & 0xFFFF0000u);
    }
  }
  for (int i = threadIdx.x; i < BB * 15; i += 256) {   // zero k in [330,360)
    int b = i / 15, d = i - b * 15;
    lxd[b * (KPAD / 2) + 165 + d] = 0u;
  }
}

// ---------------- gate: sigmoid(x@W+bias); r*hx -> x0p (f>=2), u -> ubuf -----
__global__ __launch_bounds__(256) void gate_mfma(
    const u16* __restrict__ m0, const u16* __restrict__ m1,
    const u16* __restrict__ m2, const u16* __restrict__ m3,
    const u16* __restrict__ m4,
    const u16* __restrict__ Wt, const float* __restrict__ bias,
    const float* __restrict__ hx,
    u16* __restrict__ x0p, float* __restrict__ ubuf) {
  __shared__ u16 lx[BB * KPAD];
  __shared__ u16 lt[UU * BB];           // r*hx transpose staging [o][b]
  int n = blockIdx.x;
  stage_mats_t(lx, n, m0, m1, m2, m3, m4);
  __syncthreads();
  int lane = threadIdx.x & 63;
  int w = threadIdx.x >> 6;
  int Mtile = w & 1;
  int Nbase = (w >> 1) * 4;             // waves 0,1 -> o 0..63 ; waves 2,3 -> 64..127
  int colo = lane & 15;
  int quad = lane >> 4;
  float4v acc[4];
#pragma unroll
  for (int t = 0; t < 4; ++t) {
    float bv = bias[(Nbase + t) * 16 + colo];
    acc[t] = (float4v){bv, bv, bv, bv};
  }
  const u16* arow = &lx[(Mtile * 16 + colo) * KPAD];
  for (int ks = 0; ks < KSTEPS; ++ks) {
    short8 af = *(const short8*)(arow + ks * 32 + quad * 8);
#pragma unroll
    for (int t = 0; t < 4; ++t) {
      const u16* wrow = Wt + (size_t)((Nbase + t) * 16 + colo) * KPAD + ks * 32 + quad * 8;
      short8 bf = *(const short8*)wrow;
      acc[t] = __builtin_amdgcn_mfma_f32_16x16x32_bf16(af, bf, acc[t], 0, 0, 0);
    }
  }
  int brow0 = Mtile * 16 + quad * 4;
#pragma unroll
  for (int t = 0; t < 4; ++t) {
    int o = (Nbase + t) * 16 + colo;
#pragma unroll
    for (int r = 0; r < 4; ++r) {
      int b = brow0 + r;
      float s = sigmoidf_(acc[t][r]);
      if (o < UU) {
        float h = hx[(size_t)b * (NN * UU) + (size_t)n * UU + o];
        lt[o * BB + b] = f2bf(s * h);
      } else {
        ubuf[(size_t)n * (BB * UU) + b * UU + (o - UU)] = s;
      }
    }
  }
  __syncthreads();
  // copy lt -> x0p row, dwords 32..1055 (f>=2); f<2 (inputs) stays from build_x0
  unsigned* xrow = (unsigned*)(x0p + (size_t)n * CC);
  const unsigned* ltd = (const unsigned*)lt;
  for (int j = threadIdx.x; j < UU * BB / 2; j += 256)
    xrow[32 + j] = ltd[j];
}

// ---------------- candidate + final combine ----------------------------------
__global__ __launch_bounds__(256) void cand_mfma(
    const u16* __restrict__ m0, const u16* __restrict__ m1,
    const u16* __restrict__ m2, const u16* __restrict__ m3,
    const u16* __restrict__ m4,
    const u16* __restrict__ W2t, const float* __restrict__ b2,
    const float* __restrict__ hx, const float* __restrict__ ubuf,
    float* __restrict__ out) {
  __shared__ u16 lx[BB * KPAD];
  int n = blockIdx.x;
  stage_mats_t(lx, n, m0, m1, m2, m3, m4);
  __syncthreads();
  int lane = threadIdx.x & 63;
  int w = threadIdx.x >> 6;
  int Mtile = w & 1;
  int Nbase = (w >> 1) * 2;             // o 0..63 over 4 N-tiles
  int colo = lane & 15;
  int quad = lane >> 4;
  float4v acc[2];
#pragma unroll
  for (int t = 0; t < 2; ++t) {
    float bv = b2[(Nbase + t) * 16 + colo];
    acc[t] = (float4v){bv, bv, bv, bv};
  }
  const u16* arow = &lx[(Mtile * 16 + colo) * KPAD];
  for (int ks = 0; ks < KSTEPS; ++ks) {
    short8 af = *(const short8*)(arow + ks * 32 + quad * 8);
#pragma unroll
    for (int t = 0; t < 2; ++t) {
      const u16* wrow = W2t + (size_t)((Nbase + t) * 16 + colo) * KPAD + ks * 32 + quad * 8;
      short8 bf = *(const short8*)wrow;
      acc[t] = __builtin_amdgcn_mfma_f32_16x16x32_bf16(af, bf, acc[t], 0, 0, 0);
    }
  }
  int brow0 = Mtile * 16 + quad * 4;
#pragma unroll
  for (int t = 0; t < 2; ++t) {
    int o = (Nbase + t) * 16 + colo;
#pragma unroll
    for (int r = 0; r < 4; ++r) {
      int b = brow0 + r;
      float c = tanhf_(acc[t][r]);
      float u = ubuf[(size_t)n * (BB * UU) + b * UU + o];
      float h = hx[(size_t)b * (NN * UU) + (size_t)n * UU + o];
      out[(size_t)b * (NN * UU) + (size_t)n * UU + o] = u * h + (1.0f - u) * c;
    }
  }
}

extern "C" void kernel_launch(void* const* d_in, const int* in_sizes, int n_in,
                              void* d_out, int out_size, void* d_ws, size_t ws_size,
                              hipStream_t stream) {
  const float* inp  = (const float*)d_in[0];
  const float* hx   = (const float*)d_in[1];
  const float* S0   = (const float*)d_in[2];
  const float* S1   = (const float*)d_in[3];
  const float* W    = (const float*)d_in[4];
  const float* bias = (const float*)d_in[5];
  const float* W2   = (const float*)d_in[6];
  const float* b2   = (const float*)d_in[7];
  float* out = (float*)d_out;

  char* ws = (char*)d_ws;
  const size_t MATB = (size_t)NN * CC * sizeof(u16);   // 17,301,504 B
  u16* bufA = (u16*)(ws);
  u16* bufB = (u16*)(ws + 1 * MATB);
  u16* bufC = (u16*)(ws + 2 * MATB);
  u16* bufD = (u16*)(ws + 3 * MATB);
  u16* bufE = (u16*)(ws + 4 * MATB);
  u16* bufF = (u16*)(ws + 5 * MATB);
  char* p = ws + 6 * MATB;
  float* ubuf = (float*)p;                 p += (size_t)NN * BB * UU * 4;
  int*   cols = (int*)p;                   p += 2 * (size_t)NN * CAP * 4;
  float* vals = (float*)p;                 p += 2 * (size_t)NN * CAP * 4;
  int*   nnzA = (int*)p;                   p += 2 * (size_t)NN * 4;
  u16*   Wt   = (u16*)p;                   p += (size_t)128 * KPAD * 2;
  u16*   W2t  = (u16*)p;

  prep_w<<<(192 * KPAD + 255) / 256, 256, 0, stream>>>(W, W2, Wt, W2t);
  extract_csr<<<dim3(NN / 4, 2), 256, 0, stream>>>(S0, S1, cols, vals, nnzA);
  build_x0<<<NN, 256, 0, stream>>>(inp, hx, bufA);

  // gconv1: hop1 both supports (same source A); cheb per-support
  spmm_panel<<<dim3(8192, 2), 256, 0, stream>>>(cols, vals, nnzA,
      bufA, bufA, nullptr, 1.f, 0.f, 0, bufB, bufD);
  spmm_panel<<<dim3(8192, 1), 256, 0, stream>>>(cols, vals, nnzA,
      bufB, bufB, bufA, 2.f, -1.f, 0, bufC, bufC);
  spmm_panel<<<dim3(8192, 1), 256, 0, stream>>>(cols, vals, nnzA,
      bufD, bufD, bufA, 2.f, -1.f, 1, bufE, bufE);

  // gate: writes r*hx into bufA (f>=2), u -> ubuf
  gate_mfma<<<NN, 256, 0, stream>>>(bufA, bufB, bufC, bufD, bufE,
                                    Wt, bias, hx, bufA, ubuf);

  // gconv2 on x0' = bufA
  spmm_panel<<<dim3(8192, 2), 256, 0, stream>>>(cols, vals, nnzA,
      bufA, bufA, nullptr, 1.f, 0.f, 0, bufC, bufE);
  spmm_panel<<<dim3(8192, 1), 256, 0, stream>>>(cols, vals, nnzA,
      bufC, bufC, bufA, 2.f, -1.f, 0, bufD, bufD);
  spmm_panel<<<dim3(8192, 1), 256, 0, stream>>>(cols, vals, nnzA,
      bufE, bufE, bufA, 2.f, -1.f, 1, bufF, bufF);

  // candidate + final combine
  cand_mfma<<<NN, 256, 0, stream>>>(bufA, bufC, bufD, bufE, bufF,
                                    W2t, b2, hx, ubuf, out);
}

// Round 4
// 981.076 us; speedup vs baseline: 1.1430x; 1.1430x over previous
//
#include <hip/hip_runtime.h>
#include <math.h>

// DCGRU cell, N=4096, B=32, U=64, F=66, M=5, 2 supports.
// R4: x layout [n][b*66+f] bf16 (b-major, f-contig). SpMM: 8 flat panels of
// 264 elem (528 B) pinned to XCD via blockIdx.x&7; k-loop unrolled 8x with
// scalar CSR loads for 8 outstanding gathers (latency -> L2-BW bound).
// Gate/cand MFMA staging is now a straight contiguous copy (no repack).

#define NN 4096
#define BB 32
#define UU 64
#define FF 66
#define MM 5
#define CC (BB*FF)     // 2112 elements per x row (4224 B bf16)
#define CAP 128        // max nnz/row (mean ~41)
#define PAN 264        // elements per panel (8 panels * 264 = 2112)
#define KPAD 360       // lx row stride in bf16 (720 B)
#define KSTEPS 11      // 11*32 = 352 >= 330

typedef unsigned short u16;
typedef __attribute__((ext_vector_type(8))) short short8;
typedef __attribute__((ext_vector_type(4))) float float4v;

__device__ __forceinline__ u16 f2bf(float f) {
  unsigned u = __float_as_uint(f);
  u += 0x7FFFu + ((u >> 16) & 1u);   // RNE
  return (u16)(u >> 16);
}
__device__ __forceinline__ unsigned pack2(float lo, float hi) {
  return (unsigned)f2bf(lo) | ((unsigned)f2bf(hi) << 16);
}
__device__ __forceinline__ float bflo(unsigned d) { return __uint_as_float(d << 16); }
__device__ __forceinline__ float bfhi(unsigned d) { return __uint_as_float(d & 0xFFFF0000u); }

__device__ __forceinline__ float sigmoidf_(float x) {
  return 1.0f / (1.0f + __expf(-x));
}
__device__ __forceinline__ float tanhf_(float x) {
  x = fminf(fmaxf(x, -15.f), 15.f);
  float e = __expf(2.f * x);
  return (e - 1.f) / (e + 1.f);
}

// ---------------- CSR extraction: one wave per row, order-preserving ---------
__global__ __launch_bounds__(256) void extract_csr(
    const float* __restrict__ S0, const float* __restrict__ S1,
    int* __restrict__ cols, float* __restrict__ vals, int* __restrict__ nnz) {
  int wave = threadIdx.x >> 6;
  int lane = threadIdx.x & 63;
  int row  = blockIdx.x * 4 + wave;
  int sup  = blockIdx.y;
  const float* srow = (sup ? S1 : S0) + (size_t)row * NN;
  int*   crow = cols + ((size_t)sup * NN + row) * CAP;
  float* vrow = vals + ((size_t)sup * NN + row) * CAP;
  int base = 0;
  for (int j0 = 0; j0 < NN; j0 += 64) {
    float v = srow[j0 + lane];
    unsigned long long mask = __ballot(v != 0.0f);
    if (v != 0.0f) {
      int pos = base + __popcll(mask & ((1ull << lane) - 1ull));
      if (pos < CAP) { crow[pos] = j0 + lane; vrow[pos] = v; }
    }
    base += __popcll(mask);
  }
  if (lane == 0) nnz[sup * NN + row] = (base < CAP) ? base : CAP;
}

// ---------------- weight prep: W -> Wt[o][k=m*66+f] bf16, zero-pad to KPAD ---
__global__ __launch_bounds__(256) void prep_w(
    const float* __restrict__ W, const float* __restrict__ W2,
    u16* __restrict__ Wt, u16* __restrict__ W2t) {
  int idx = blockIdx.x * 256 + threadIdx.x;
  if (idx < 128 * KPAD) {
    int o = idx / KPAD, k = idx - o * KPAD;
    float v = 0.f;
    if (k < 330) { int m = k / FF, f = k - m * FF; v = W[((size_t)f * MM + m) * 128 + o]; }
    Wt[(size_t)o * KPAD + k] = f2bf(v);
  } else if (idx < 192 * KPAD) {
    int i = idx - 128 * KPAD;
    int o = i / KPAD, k = i - o * KPAD;
    float v = 0.f;
    if (k < 330) { int m = k / FF, f = k - m * FF; v = W2[((size_t)f * MM + m) * UU + o]; }
    W2t[(size_t)o * KPAD + k] = f2bf(v);
  }
}

// ---------------- build x0[n][b*66+f] bf16 -----------------------------------
__global__ __launch_bounds__(256) void build_x0(
    const float* __restrict__ inp, const float* __restrict__ hx,
    u16* __restrict__ x0) {
  int n = blockIdx.x;
  unsigned* xr = (unsigned*)(x0 + (size_t)n * CC);
  for (int j = threadIdx.x; j < CC / 2; j += 256) {   // 1056 dwords, 33 per b
    int b = j / 33, f = (j - b * 33) * 2;
    float lo, hi;
    if (f == 0) {
      lo = inp[(size_t)b * (NN * 2) + n * 2];
      hi = inp[(size_t)b * (NN * 2) + n * 2 + 1];
    } else {
      const float* h = hx + (size_t)b * (NN * UU) + (size_t)n * UU + (f - 2);
      lo = h[0]; hi = h[1];
    }
    xr[j] = pack2(lo, hi);
  }
}

// ---------------- SpMM: flat panels, panel==XCD pinning, 8x unrolled ---------
// grid (8192, ny): blockIdx.x = rowgrp*8 + panel; 4 waves = 4 rows/block.
__device__ __forceinline__ void fma4(float v, uint2 q, float* a) {
  a[0] = fmaf(v, bflo(q.x), a[0]);
  a[1] = fmaf(v, bfhi(q.x), a[1]);
  a[2] = fmaf(v, bflo(q.y), a[2]);
  a[3] = fmaf(v, bfhi(q.y), a[3]);
}

__global__ __launch_bounds__(256) void spmm_panel(
    const int* __restrict__ cols, const float* __restrict__ vals,
    const int* __restrict__ nnz,
    const u16* xA, const u16* xB, const u16* z,
    float alpha, float beta, int sup_base,
    u16* __restrict__ outA, u16* __restrict__ outB) {
  int panel = blockIdx.x & 7;
  int rowg  = blockIdx.x >> 3;
  int wv    = threadIdx.x >> 6;
  int lane  = threadIdx.x & 63;
  int row   = rowg * 4 + wv;
  const u16* xs = blockIdx.y ? xB : xA;
  u16* out = blockIdx.y ? outB : outA;
  int supc = sup_base + blockIdx.y;
  int srow = __builtin_amdgcn_readfirstlane(supc * NN + row);
  const int*   crow = cols + (size_t)srow * CAP;
  const float* vrow = vals + (size_t)srow * CAP;
  int cnt = nnz[srow];
  const u16* xsp = xs + panel * PAN + lane * 4;
  bool ext = lane < 2;                 // elements 256..263 of the panel
  float a0[4] = {0.f, 0.f, 0.f, 0.f};
  float a1[4] = {0.f, 0.f, 0.f, 0.f};

  int kmain = cnt & ~7;
  for (int k0 = 0; k0 < kmain; k0 += 8) {
    int   cc8[8];
    float vv8[8];
#pragma unroll
    for (int i = 0; i < 8; ++i) { cc8[i] = crow[k0 + i]; vv8[i] = vrow[k0 + i]; }
    uint2 q[8];
#pragma unroll
    for (int i = 0; i < 8; ++i) q[i] = *(const uint2*)(xsp + cc8[i] * CC);
#pragma unroll
    for (int i = 0; i < 8; ++i) fma4(vv8[i], q[i], a0);
    if (ext) {
#pragma unroll
      for (int i = 0; i < 8; ++i) {
        uint2 t = *(const uint2*)(xsp + cc8[i] * CC + 256);
        fma4(vv8[i], t, a1);
      }
    }
  }
  for (int k = kmain; k < cnt; ++k) {
    int c = crow[k]; float v = vrow[k];
    uint2 q = *(const uint2*)(xsp + c * CC);
    fma4(v, q, a0);
    if (ext) {
      uint2 t = *(const uint2*)(xsp + c * CC + 256);
      fma4(v, t, a1);
    }
  }

  size_t obase = (size_t)row * CC + panel * PAN + lane * 4;
  float r0 = alpha * a0[0], r1 = alpha * a0[1];
  float r2 = alpha * a0[2], r3 = alpha * a0[3];
  if (z) {
    uint2 zq = *(const uint2*)(z + obase);
    r0 += beta * bflo(zq.x); r1 += beta * bfhi(zq.x);
    r2 += beta * bflo(zq.y); r3 += beta * bfhi(zq.y);
  }
  *(uint2*)(out + obase) = make_uint2(pack2(r0, r1), pack2(r2, r3));
  if (ext) {
    float s0 = alpha * a1[0], s1 = alpha * a1[1];
    float s2 = alpha * a1[2], s3 = alpha * a1[3];
    if (z) {
      uint2 zq = *(const uint2*)(z + obase + 256);
      s0 += beta * bflo(zq.x); s1 += beta * bfhi(zq.x);
      s2 += beta * bflo(zq.y); s3 += beta * bfhi(zq.y);
    }
    *(uint2*)(out + obase + 256) = make_uint2(pack2(s0, s1), pack2(s2, s3));
  }
}

// ---------------- staging: 5 mats [b][f] -> lx[b][k=m*66+f] straight copy ----
__device__ __forceinline__ void stage_mats(
    u16* lx, int n,
    const u16* m0, const u16* m1, const u16* m2, const u16* m3, const u16* m4) {
  unsigned* lxd = (unsigned*)lx;
#pragma unroll
  for (int m = 0; m < MM; ++m) {
    const u16* src = (m == 0) ? m0 : (m == 1) ? m1 : (m == 2) ? m2 : (m == 3) ? m3 : m4;
    const unsigned* s = (const unsigned*)(src + (size_t)n * CC);
    for (int j = threadIdx.x; j < CC / 2; j += 256) {   // 1056 dwords, 33/b
      int b = j / 33, f2 = j - b * 33;
      lxd[b * (KPAD / 2) + m * 33 + f2] = s[j];
    }
  }
  for (int i = threadIdx.x; i < BB * 15; i += 256) {    // zero k in [330,360)
    int b = i / 15, d = i - b * 15;
    lxd[b * (KPAD / 2) + 165 + d] = 0u;
  }
}

// ---------------- gate: sigmoid(x@W+bias); r*hx -> x0p (f>=2), u -> ubuf -----
__global__ __launch_bounds__(256) void gate_mfma(
    const u16* m0, const u16* __restrict__ m1,
    const u16* __restrict__ m2, const u16* __restrict__ m3,
    const u16* __restrict__ m4,
    const u16* __restrict__ Wt, const float* __restrict__ bias,
    const float* __restrict__ hx,
    u16* x0p, float* __restrict__ ubuf) {
  __shared__ u16 lx[BB * KPAD];
  __shared__ u16 lt[BB * UU];           // r*hx staging [b][o]
  int n = blockIdx.x;
  stage_mats(lx, n, m0, m1, m2, m3, m4);
  __syncthreads();
  int lane = threadIdx.x & 63;
  int w = threadIdx.x >> 6;
  int Mtile = w & 1;
  int Nbase = (w >> 1) * 4;             // waves 0,1 -> o 0..63; waves 2,3 -> 64..127
  int colo = lane & 15;
  int quad = lane >> 4;
  float4v acc[4];
#pragma unroll
  for (int t = 0; t < 4; ++t) {
    float bv = bias[(Nbase + t) * 16 + colo];
    acc[t] = (float4v){bv, bv, bv, bv};
  }
  const u16* arow = &lx[(Mtile * 16 + colo) * KPAD];
  for (int ks = 0; ks < KSTEPS; ++ks) {
    short8 af = *(const short8*)(arow + ks * 32 + quad * 8);
#pragma unroll
    for (int t = 0; t < 4; ++t) {
      const u16* wrow = Wt + (size_t)((Nbase + t) * 16 + colo) * KPAD + ks * 32 + quad * 8;
      short8 bf = *(const short8*)wrow;
      acc[t] = __builtin_amdgcn_mfma_f32_16x16x32_bf16(af, bf, acc[t], 0, 0, 0);
    }
  }
  int brow0 = Mtile * 16 + quad * 4;
#pragma unroll
  for (int t = 0; t < 4; ++t) {
    int o = (Nbase + t) * 16 + colo;
#pragma unroll
    for (int r = 0; r < 4; ++r) {
      int b = brow0 + r;
      float s = sigmoidf_(acc[t][r]);
      if (o < UU) {
        float h = hx[(size_t)b * (NN * UU) + (size_t)n * UU + o];
        lt[b * UU + o] = f2bf(s * h);
      } else {
        ubuf[(size_t)n * (BB * UU) + b * UU + (o - UU)] = s;
      }
    }
  }
  __syncthreads();
  // copy lt -> x0p row: per b, dwords 1..32 (f = 2..65); dword 0 (f=0,1) kept
  unsigned* xrow = (unsigned*)(x0p + (size_t)n * CC);
  const unsigned* ltd = (const unsigned*)lt;
  for (int j = threadIdx.x; j < BB * 32; j += 256) {
    int b = j >> 5, od = j & 31;
    xrow[b * 33 + 1 + od] = ltd[j];
  }
}

// ---------------- candidate + final combine ----------------------------------
__global__ __launch_bounds__(256) void cand_mfma(
    const u16* __restrict__ m0, const u16* __restrict__ m1,
    const u16* __restrict__ m2, const u16* __restrict__ m3,
    const u16* __restrict__ m4,
    const u16* __restrict__ W2t, const float* __restrict__ b2,
    const float* __restrict__ hx, const float* __restrict__ ubuf,
    float* __restrict__ out) {
  __shared__ u16 lx[BB * KPAD];
  int n = blockIdx.x;
  stage_mats(lx, n, m0, m1, m2, m3, m4);
  __syncthreads();
  int lane = threadIdx.x & 63;
  int w = threadIdx.x >> 6;
  int Mtile = w & 1;
  int Nbase = (w >> 1) * 2;             // o 0..63 over 4 N-tiles
  int colo = lane & 15;
  int quad = lane >> 4;
  float4v acc[2];
#pragma unroll
  for (int t = 0; t < 2; ++t) {
    float bv = b2[(Nbase + t) * 16 + colo];
    acc[t] = (float4v){bv, bv, bv, bv};
  }
  const u16* arow = &lx[(Mtile * 16 + colo) * KPAD];
  for (int ks = 0; ks < KSTEPS; ++ks) {
    short8 af = *(const short8*)(arow + ks * 32 + quad * 8);
#pragma unroll
    for (int t = 0; t < 2; ++t) {
      const u16* wrow = W2t + (size_t)((Nbase + t) * 16 + colo) * KPAD + ks * 32 + quad * 8;
      short8 bf = *(const short8*)wrow;
      acc[t] = __builtin_amdgcn_mfma_f32_16x16x32_bf16(af, bf, acc[t], 0, 0, 0);
    }
  }
  int brow0 = Mtile * 16 + quad * 4;
#pragma unroll
  for (int t = 0; t < 2; ++t) {
    int o = (Nbase + t) * 16 + colo;
#pragma unroll
    for (int r = 0; r < 4; ++r) {
      int b = brow0 + r;
      float c = tanhf_(acc[t][r]);
      float u = ubuf[(size_t)n * (BB * UU) + b * UU + o];
      float h = hx[(size_t)b * (NN * UU) + (size_t)n * UU + o];
      out[(size_t)b * (NN * UU) + (size_t)n * UU + o] = u * h + (1.0f - u) * c;
    }
  }
}

extern "C" void kernel_launch(void* const* d_in, const int* in_sizes, int n_in,
                              void* d_out, int out_size, void* d_ws, size_t ws_size,
                              hipStream_t stream) {
  const float* inp  = (const float*)d_in[0];
  const float* hx   = (const float*)d_in[1];
  const float* S0   = (const float*)d_in[2];
  const float* S1   = (const float*)d_in[3];
  const float* W    = (const float*)d_in[4];
  const float* bias = (const float*)d_in[5];
  const float* W2   = (const float*)d_in[6];
  const float* b2   = (const float*)d_in[7];
  float* out = (float*)d_out;

  char* ws = (char*)d_ws;
  const size_t MATB = (size_t)NN * CC * sizeof(u16);   // 17,301,504 B
  u16* bufA = (u16*)(ws);
  u16* bufB = (u16*)(ws + 1 * MATB);
  u16* bufC = (u16*)(ws + 2 * MATB);
  u16* bufD = (u16*)(ws + 3 * MATB);
  u16* bufE = (u16*)(ws + 4 * MATB);
  u16* bufF = (u16*)(ws + 5 * MATB);
  char* p = ws + 6 * MATB;
  float* ubuf = (float*)p;                 p += (size_t)NN * BB * UU * 4;
  int*   cols = (int*)p;                   p += 2 * (size_t)NN * CAP * 4;
  float* vals = (float*)p;                 p += 2 * (size_t)NN * CAP * 4;
  int*   nnzA = (int*)p;                   p += 2 * (size_t)NN * 4;
  u16*   Wt   = (u16*)p;                   p += (size_t)128 * KPAD * 2;
  u16*   W2t  = (u16*)p;

  prep_w<<<(192 * KPAD + 255) / 256, 256, 0, stream>>>(W, W2, Wt, W2t);
  extract_csr<<<dim3(NN / 4, 2), 256, 0, stream>>>(S0, S1, cols, vals, nnzA);
  build_x0<<<NN, 256, 0, stream>>>(inp, hx, bufA);

  // gconv1: hop1 both supports (same source A); cheb per-support
  spmm_panel<<<dim3(8192, 2), 256, 0, stream>>>(cols, vals, nnzA,
      bufA, bufA, nullptr, 1.f, 0.f, 0, bufB, bufD);
  spmm_panel<<<dim3(8192, 1), 256, 0, stream>>>(cols, vals, nnzA,
      bufB, bufB, bufA, 2.f, -1.f, 0, bufC, bufC);
  spmm_panel<<<dim3(8192, 1), 256, 0, stream>>>(cols, vals, nnzA,
      bufD, bufD, bufA, 2.f, -1.f, 1, bufE, bufE);

  // gate: writes r*hx into bufA (f>=2), u -> ubuf
  gate_mfma<<<NN, 256, 0, stream>>>(bufA, bufB, bufC, bufD, bufE,
                                    Wt, bias, hx, bufA, ubuf);

  // gconv2 on x0' = bufA
  spmm_panel<<<dim3(8192, 2), 256, 0, stream>>>(cols, vals, nnzA,
      bufA, bufA, nullptr, 1.f, 0.f, 0, bufC, bufE);
  spmm_panel<<<dim3(8192, 1), 256, 0, stream>>>(cols, vals, nnzA,
      bufC, bufC, bufA, 2.f, -1.f, 0, bufD, bufD);
  spmm_panel<<<dim3(8192, 1), 256, 0, stream>>>(cols, vals, nnzA,
      bufE, bufE, bufA, 2.f, -1.f, 1, bufF, bufF);

  // candidate + final combine
  cand_mfma<<<NN, 256, 0, stream>>>(bufA, bufC, bufD, bufE, bufF,
                                    W2t, b2, hx, ubuf, out);
}

// Round 5
// 789.151 us; speedup vs baseline: 1.4210x; 1.2432x over previous
//
#include <hip/hip_runtime.h>
#include <math.h>

// DCGRU cell, N=4096, B=32, U=64, F=66, M=5, 2 supports.
// R5: x split into xi[n][b*2] (128 B row) + xh[n][b*64] (4096 B row) so SpMM
// panels are exactly 8 x 512 B (64 lanes x uint2, no ragged lanes), panel==XCD
// pinned via bx&7. CSR rows zero-padded to multiple of 8 (no tail loop).
// __launch_bounds__(256,2) so 8 gathers stay live in VGPRs (R4 had VGPR=32 ->
// serialized loads). MFMA gate/cand kept; staging is pure shift-indexed copies.

#define NN 4096
#define BB 32
#define UU 64
#define FF 66
#define MM 5
#define XHC 2048       // xh row elements (4096 B)
#define XIC 64         // xi row elements (128 B)
#define CAP 128        // max nnz/row (mean ~41), multiple of 8
#define KPAD 360       // lx/W row stride in bf16 (720 B)
#define KSTEPS 11      // 11*32 = 352 >= 330

typedef unsigned short u16;
typedef __attribute__((ext_vector_type(8))) short short8;
typedef __attribute__((ext_vector_type(4))) float float4v;

__device__ __forceinline__ u16 f2bf(float f) {
  unsigned u = __float_as_uint(f);
  u += 0x7FFFu + ((u >> 16) & 1u);   // RNE
  return (u16)(u >> 16);
}
__device__ __forceinline__ unsigned pack2(float lo, float hi) {
  return (unsigned)f2bf(lo) | ((unsigned)f2bf(hi) << 16);
}
__device__ __forceinline__ float bflo(unsigned d) { return __uint_as_float(d << 16); }
__device__ __forceinline__ float bfhi(unsigned d) { return __uint_as_float(d & 0xFFFF0000u); }

__device__ __forceinline__ float sigmoidf_(float x) {
  return 1.0f / (1.0f + __expf(-x));
}
__device__ __forceinline__ float tanhf_(float x) {
  x = fminf(fmaxf(x, -15.f), 15.f);
  float e = __expf(2.f * x);
  return (e - 1.f) / (e + 1.f);
}

// ---------------- CSR extraction: one wave per row; rows zero-padded to %8 --
__global__ __launch_bounds__(256) void extract_csr(
    const float* __restrict__ S0, const float* __restrict__ S1,
    int* __restrict__ cols, float* __restrict__ vals, int* __restrict__ nnz) {
  int wave = threadIdx.x >> 6;
  int lane = threadIdx.x & 63;
  int row  = blockIdx.x * 4 + wave;
  int sup  = blockIdx.y;
  const float* srow = (sup ? S1 : S0) + (size_t)row * NN;
  int*   crow = cols + ((size_t)sup * NN + row) * CAP;
  float* vrow = vals + ((size_t)sup * NN + row) * CAP;
  int base = 0;
  for (int j0 = 0; j0 < NN; j0 += 64) {
    float v = srow[j0 + lane];
    unsigned long long mask = __ballot(v != 0.0f);
    if (v != 0.0f) {
      int pos = base + __popcll(mask & ((1ull << lane) - 1ull));
      if (pos < CAP) { crow[pos] = j0 + lane; vrow[pos] = v; }
    }
    base += __popcll(mask);
  }
  if (base > CAP) base = CAP;
  int padded = (base + 7) & ~7;
  if (padded > CAP) padded = CAP;
  int p = base + lane;
  if (p < padded) { crow[p] = 0; vrow[p] = 0.0f; }
  if (lane == 0) nnz[sup * NN + row] = padded;
}

// ---------------- weight prep: W -> Wt[o][k=m*66+f] bf16, zero-pad to KPAD --
__global__ __launch_bounds__(256) void prep_w(
    const float* __restrict__ W, const float* __restrict__ W2,
    u16* __restrict__ Wt, u16* __restrict__ W2t) {
  int idx = blockIdx.x * 256 + threadIdx.x;
  if (idx < 128 * KPAD) {
    int o = idx / KPAD, k = idx - o * KPAD;
    float v = 0.f;
    if (k < 330) { int m = k / FF, f = k - m * FF; v = W[((size_t)f * MM + m) * 128 + o]; }
    Wt[(size_t)o * KPAD + k] = f2bf(v);
  } else if (idx < 192 * KPAD) {
    int i = idx - 128 * KPAD;
    int o = i / KPAD, k = i - o * KPAD;
    float v = 0.f;
    if (k < 330) { int m = k / FF, f = k - m * FF; v = W2[((size_t)f * MM + m) * UU + o]; }
    W2t[(size_t)o * KPAD + k] = f2bf(v);
  }
}

// ---------------- build xi0 / xh0 -------------------------------------------
__global__ __launch_bounds__(256) void build_x0(
    const float* __restrict__ inp, const float* __restrict__ hx,
    u16* __restrict__ xi0, u16* __restrict__ xh0) {
  int n = blockIdx.x;
  unsigned* xhd = (unsigned*)(xh0 + (size_t)n * XHC);
  for (int j = threadIdx.x; j < XHC / 2; j += 256) {   // 1024 dwords
    int b = j >> 5, f2 = (j & 31) * 2;
    const float* h = hx + (size_t)b * (NN * UU) + (size_t)n * UU + f2;
    xhd[j] = pack2(h[0], h[1]);
  }
  if (threadIdx.x < 32) {
    int b = threadIdx.x;
    unsigned* xid = (unsigned*)(xi0 + (size_t)n * XIC);
    xid[b] = pack2(inp[(size_t)b * (NN * 2) + n * 2],
                   inp[(size_t)b * (NN * 2) + n * 2 + 1]);
  }
}

// ---------------- SpMM: 8 x 512 B panels, panel==XCD, 8-deep pipeline -------
__device__ __forceinline__ void fma4(float v, uint2 q, float* a) {
  a[0] = fmaf(v, bflo(q.x), a[0]);
  a[1] = fmaf(v, bfhi(q.x), a[1]);
  a[2] = fmaf(v, bflo(q.y), a[2]);
  a[3] = fmaf(v, bfhi(q.y), a[3]);
}

__global__ __launch_bounds__(256, 2) void spmm_panel(
    const int* __restrict__ cols, const float* __restrict__ vals,
    const int* __restrict__ nnz,
    const u16* xiA, const u16* xhA, const u16* xiB, const u16* xhB,
    const u16* zi, const u16* zh,
    float alpha, float beta, int sup_base,
    u16* yiA, u16* yhA, u16* yiB, u16* yhB) {
  int panel = blockIdx.x & 7;
  int lane  = threadIdx.x & 63;
  int wv    = threadIdx.x >> 6;
  int row   = (blockIdx.x >> 3) * 4 + wv;
  const u16* xi = blockIdx.y ? xiB : xiA;
  const u16* xh = blockIdx.y ? xhB : xhA;
  u16* yi = blockIdx.y ? yiB : yiA;
  u16* yh = blockIdx.y ? yhB : yhA;
  int srow = __builtin_amdgcn_readfirstlane((sup_base + blockIdx.y) * NN + row);
  const int*   crow = cols + (size_t)srow * CAP;
  const float* vrow = vals + (size_t)srow * CAP;
  int cnt = nnz[srow];                       // multiple of 8, vals padded w/ 0
  const u16* xph = xh + panel * 256 + lane * 4;
  float ah[4] = {0.f, 0.f, 0.f, 0.f};
  float ai[2] = {0.f, 0.f};

  if (panel == 0) {
    const u16* xpi = xi + (lane & 31) * 2;
    for (int k0 = 0; k0 < cnt; k0 += 8) {
      int cc8[8]; float vv8[8];
#pragma unroll
      for (int i = 0; i < 8; ++i) { cc8[i] = crow[k0 + i]; vv8[i] = vrow[k0 + i]; }
      uint2 qh[8];
#pragma unroll
      for (int i = 0; i < 8; ++i) qh[i] = *(const uint2*)(xph + (size_t)cc8[i] * XHC);
      unsigned qi[8];
      if (lane < 32) {
#pragma unroll
        for (int i = 0; i < 8; ++i) qi[i] = *(const unsigned*)(xpi + (size_t)cc8[i] * XIC);
      }
#pragma unroll
      for (int i = 0; i < 8; ++i) fma4(vv8[i], qh[i], ah);
      if (lane < 32) {
#pragma unroll
        for (int i = 0; i < 8; ++i) {
          ai[0] = fmaf(vv8[i], bflo(qi[i]), ai[0]);
          ai[1] = fmaf(vv8[i], bfhi(qi[i]), ai[1]);
        }
      }
    }
  } else {
    for (int k0 = 0; k0 < cnt; k0 += 8) {
      int cc8[8]; float vv8[8];
#pragma unroll
      for (int i = 0; i < 8; ++i) { cc8[i] = crow[k0 + i]; vv8[i] = vrow[k0 + i]; }
      uint2 qh[8];
#pragma unroll
      for (int i = 0; i < 8; ++i) qh[i] = *(const uint2*)(xph + (size_t)cc8[i] * XHC);
#pragma unroll
      for (int i = 0; i < 8; ++i) fma4(vv8[i], qh[i], ah);
    }
  }

  size_t oh = (size_t)row * XHC + panel * 256 + lane * 4;
  float r0 = alpha * ah[0], r1 = alpha * ah[1];
  float r2 = alpha * ah[2], r3 = alpha * ah[3];
  if (zh) {
    uint2 zq = *(const uint2*)(zh + oh);
    r0 += beta * bflo(zq.x); r1 += beta * bfhi(zq.x);
    r2 += beta * bflo(zq.y); r3 += beta * bfhi(zq.y);
  }
  *(uint2*)(yh + oh) = make_uint2(pack2(r0, r1), pack2(r2, r3));
  if (panel == 0 && lane < 32) {
    size_t oi = (size_t)row * XIC + lane * 2;
    float s0 = alpha * ai[0], s1 = alpha * ai[1];
    if (zi) {
      unsigned zq = *(const unsigned*)(zi + oi);
      s0 += beta * bflo(zq); s1 += beta * bfhi(zq);
    }
    *(unsigned*)(yi + oi) = pack2(s0, s1);
  }
}

// ---------------- staging: 5 (xi,xh) mats -> lx[b][k=m*66+f], pad zeroed ----
__device__ __forceinline__ void stage_one(
    unsigned* lxd, int n, int m, const u16* xim, const u16* xhm) {
  const unsigned* sh = (const unsigned*)(xhm + (size_t)n * XHC);
  for (int j = threadIdx.x; j < XHC / 2; j += 256) {    // 1024 dwords
    int b = j >> 5, f2d = j & 31;
    lxd[b * (KPAD / 2) + m * 33 + 1 + f2d] = sh[j];
  }
  if (threadIdx.x < 32) {
    const unsigned* si = (const unsigned*)(xim + (size_t)n * XIC);
    lxd[threadIdx.x * (KPAD / 2) + m * 33] = si[threadIdx.x];
  }
}
__device__ __forceinline__ void stage_mats(
    unsigned* lxd, int n,
    const u16* i0, const u16* i1, const u16* i2, const u16* i3, const u16* i4,
    const u16* h0, const u16* h1, const u16* h2, const u16* h3, const u16* h4) {
  stage_one(lxd, n, 0, i0, h0);
  stage_one(lxd, n, 1, i1, h1);
  stage_one(lxd, n, 2, i2, h2);
  stage_one(lxd, n, 3, i3, h3);
  stage_one(lxd, n, 4, i4, h4);
  for (int i = threadIdx.x; i < BB * 16; i += 256) {    // zero k in [330,360)
    int b = i >> 4, d = i & 15;
    if (d < 15) lxd[b * (KPAD / 2) + 165 + d] = 0u;
  }
}

// ---------------- gate: sigmoid(x@W+bias); r*hx -> xh' (in place), u->ubuf --
__global__ __launch_bounds__(256) void gate_mfma(
    const u16* i0, const u16* __restrict__ i1, const u16* __restrict__ i2,
    const u16* __restrict__ i3, const u16* __restrict__ i4,
    const u16* h0, const u16* __restrict__ h1, const u16* __restrict__ h2,
    const u16* __restrict__ h3, const u16* __restrict__ h4,
    const u16* __restrict__ Wt, const float* __restrict__ bias,
    const float* __restrict__ hx,
    u16* xhp, float* __restrict__ ubuf) {
  __shared__ u16 lx[BB * KPAD];
  __shared__ u16 lt[BB * UU];           // r*hx staging [b][o]
  int n = blockIdx.x;
  stage_mats((unsigned*)lx, n, i0, i1, i2, i3, i4, h0, h1, h2, h3, h4);
  __syncthreads();
  int lane = threadIdx.x & 63;
  int w = threadIdx.x >> 6;
  int Mtile = w & 1;
  int Nbase = (w >> 1) * 4;             // waves 0,1 -> o 0..63; waves 2,3 -> 64..127
  int colo = lane & 15;
  int quad = lane >> 4;
  float4v acc[4];
#pragma unroll
  for (int t = 0; t < 4; ++t) {
    float bv = bias[(Nbase + t) * 16 + colo];
    acc[t] = (float4v){bv, bv, bv, bv};
  }
  const u16* arow = &lx[(Mtile * 16 + colo) * KPAD];
  for (int ks = 0; ks < KSTEPS; ++ks) {
    short8 af = *(const short8*)(arow + ks * 32 + quad * 8);
#pragma unroll
    for (int t = 0; t < 4; ++t) {
      const u16* wrow = Wt + (size_t)((Nbase + t) * 16 + colo) * KPAD + ks * 32 + quad * 8;
      short8 bf = *(const short8*)wrow;
      acc[t] = __builtin_amdgcn_mfma_f32_16x16x32_bf16(af, bf, acc[t], 0, 0, 0);
    }
  }
  int brow0 = Mtile * 16 + quad * 4;
#pragma unroll
  for (int t = 0; t < 4; ++t) {
    int o = (Nbase + t) * 16 + colo;
#pragma unroll
    for (int r = 0; r < 4; ++r) {
      int b = brow0 + r;
      float s = sigmoidf_(acc[t][r]);
      if (o < UU) {
        float h = hx[(size_t)b * (NN * UU) + (size_t)n * UU + o];
        lt[b * UU + o] = f2bf(s * h);
      } else {
        ubuf[(size_t)n * (BB * UU) + b * UU + (o - UU)] = s;
      }
    }
  }
  __syncthreads();
  // xh' row n = lt (straight copy: lt[b][o] == xh[b*64+o])
  unsigned* xrow = (unsigned*)(xhp + (size_t)n * XHC);
  const unsigned* ltd = (const unsigned*)lt;
  for (int j = threadIdx.x; j < XHC / 2; j += 256)
    xrow[j] = ltd[j];
}

// ---------------- candidate + final combine ---------------------------------
__global__ __launch_bounds__(256) void cand_mfma(
    const u16* __restrict__ i0, const u16* __restrict__ i1,
    const u16* __restrict__ i2, const u16* __restrict__ i3,
    const u16* __restrict__ i4,
    const u16* __restrict__ h0, const u16* __restrict__ h1,
    const u16* __restrict__ h2, const u16* __restrict__ h3,
    const u16* __restrict__ h4,
    const u16* __restrict__ W2t, const float* __restrict__ b2,
    const float* __restrict__ hx, const float* __restrict__ ubuf,
    float* __restrict__ out) {
  __shared__ u16 lx[BB * KPAD];
  int n = blockIdx.x;
  stage_mats((unsigned*)lx, n, i0, i1, i2, i3, i4, h0, h1, h2, h3, h4);
  __syncthreads();
  int lane = threadIdx.x & 63;
  int w = threadIdx.x >> 6;
  int Mtile = w & 1;
  int Nbase = (w >> 1) * 2;             // o 0..63 over 4 N-tiles
  int colo = lane & 15;
  int quad = lane >> 4;
  float4v acc[2];
#pragma unroll
  for (int t = 0; t < 2; ++t) {
    float bv = b2[(Nbase + t) * 16 + colo];
    acc[t] = (float4v){bv, bv, bv, bv};
  }
  const u16* arow = &lx[(Mtile * 16 + colo) * KPAD];
  for (int ks = 0; ks < KSTEPS; ++ks) {
    short8 af = *(const short8*)(arow + ks * 32 + quad * 8);
#pragma unroll
    for (int t = 0; t < 2; ++t) {
      const u16* wrow = W2t + (size_t)((Nbase + t) * 16 + colo) * KPAD + ks * 32 + quad * 8;
      short8 bf = *(const short8*)wrow;
      acc[t] = __builtin_amdgcn_mfma_f32_16x16x32_bf16(af, bf, acc[t], 0, 0, 0);
    }
  }
  int brow0 = Mtile * 16 + quad * 4;
#pragma unroll
  for (int t = 0; t < 2; ++t) {
    int o = (Nbase + t) * 16 + colo;
#pragma unroll
    for (int r = 0; r < 4; ++r) {
      int b = brow0 + r;
      float c = tanhf_(acc[t][r]);
      float u = ubuf[(size_t)n * (BB * UU) + b * UU + o];
      float h = hx[(size_t)b * (NN * UU) + (size_t)n * UU + o];
      out[(size_t)b * (NN * UU) + (size_t)n * UU + o] = u * h + (1.0f - u) * c;
    }
  }
}

extern "C" void kernel_launch(void* const* d_in, const int* in_sizes, int n_in,
                              void* d_out, int out_size, void* d_ws, size_t ws_size,
                              hipStream_t stream) {
  const float* inp  = (const float*)d_in[0];
  const float* hx   = (const float*)d_in[1];
  const float* S0   = (const float*)d_in[2];
  const float* S1   = (const float*)d_in[3];
  const float* W    = (const float*)d_in[4];
  const float* bias = (const float*)d_in[5];
  const float* W2   = (const float*)d_in[6];
  const float* b2   = (const float*)d_in[7];
  float* out = (float*)d_out;

  char* ws = (char*)d_ws;
  const size_t XHB = (size_t)NN * XHC * sizeof(u16);   // 16,777,216 B
  const size_t XIB = (size_t)NN * XIC * sizeof(u16);   // 524,288 B
  u16* bufA = (u16*)(ws);              // xh0 -> xh'
  u16* bufB = (u16*)(ws + 1 * XHB);    // S0@x  (h)
  u16* bufC = (u16*)(ws + 2 * XHB);    // cheb0 (h)
  u16* bufD = (u16*)(ws + 3 * XHB);    // S1@x  (h)
  u16* bufE = (u16*)(ws + 4 * XHB);    // cheb1 (h)
  char* p = ws + 5 * XHB;
  u16* xi0 = (u16*)p;  p += XIB;       // xi (shared by both passes)
  u16* yi1 = (u16*)p;  p += XIB;
  u16* yi2 = (u16*)p;  p += XIB;
  u16* yi3 = (u16*)p;  p += XIB;
  u16* yi4 = (u16*)p;  p += XIB;
  float* ubuf = (float*)p;             p += (size_t)NN * BB * UU * 4;
  int*   cols = (int*)p;               p += 2 * (size_t)NN * CAP * 4;
  float* vals = (float*)p;             p += 2 * (size_t)NN * CAP * 4;
  int*   nnzA = (int*)p;               p += 2 * (size_t)NN * 4;
  u16*   Wt   = (u16*)p;               p += (size_t)128 * KPAD * 2;
  u16*   W2t  = (u16*)p;

  prep_w<<<(192 * KPAD + 255) / 256, 256, 0, stream>>>(W, W2, Wt, W2t);
  extract_csr<<<dim3(NN / 4, 2), 256, 0, stream>>>(S0, S1, cols, vals, nnzA);
  build_x0<<<NN, 256, 0, stream>>>(inp, hx, xi0, bufA);

  // gconv1: hop1 both supports; cheb per support
  spmm_panel<<<dim3(8192, 2), 256, 0, stream>>>(cols, vals, nnzA,
      xi0, bufA, xi0, bufA, nullptr, nullptr, 1.f, 0.f, 0,
      yi1, bufB, yi3, bufD);
  spmm_panel<<<dim3(8192, 1), 256, 0, stream>>>(cols, vals, nnzA,
      yi1, bufB, yi1, bufB, xi0, bufA, 2.f, -1.f, 0,
      yi2, bufC, yi2, bufC);
  spmm_panel<<<dim3(8192, 1), 256, 0, stream>>>(cols, vals, nnzA,
      yi3, bufD, yi3, bufD, xi0, bufA, 2.f, -1.f, 1,
      yi4, bufE, yi4, bufE);

  // gate: writes xh' in place into bufA, u -> ubuf
  gate_mfma<<<NN, 256, 0, stream>>>(xi0, yi1, yi2, yi3, yi4,
                                    bufA, bufB, bufC, bufD, bufE,
                                    Wt, bias, hx, bufA, ubuf);

  // gconv2 on x0' = (xi0, bufA)
  spmm_panel<<<dim3(8192, 2), 256, 0, stream>>>(cols, vals, nnzA,
      xi0, bufA, xi0, bufA, nullptr, nullptr, 1.f, 0.f, 0,
      yi1, bufB, yi3, bufD);
  spmm_panel<<<dim3(8192, 1), 256, 0, stream>>>(cols, vals, nnzA,
      yi1, bufB, yi1, bufB, xi0, bufA, 2.f, -1.f, 0,
      yi2, bufC, yi2, bufC);
  spmm_panel<<<dim3(8192, 1), 256, 0, stream>>>(cols, vals, nnzA,
      yi3, bufD, yi3, bufD, xi0, bufA, 2.f, -1.f, 1,
      yi4, bufE, yi4, bufE);

  // candidate + final combine
  cand_mfma<<<NN, 256, 0, stream>>>(xi0, yi1, yi2, yi3, yi4,
                                    bufA, bufB, bufC, bufD, bufE,
                                    W2t, b2, hx, ubuf, out);
}

// Round 6
// 672.727 us; speedup vs baseline: 1.6669x; 1.1731x over previous
//
#include <hip/hip_runtime.h>
#include <math.h>

// DCGRU cell, N=4096, B=32, U=64, F=66, M=5, 2 supports.
// R6: SpMM uses 4 x 1024 B panels; whole wave serves one nnz per load (uint4 x
// 64 lanes), column index stays scalar -> zero VALU address math; 16 loads in
// flight. Gate/cand weights pre-swizzled into exact MFMA B-fragment order so
// every fragment load is one coalesced 1 KB fetch (R5 had stride-720B gathers,
// 4x line amplification). Cheb singles merged into grid.y=2 pairs.

#define NN 4096
#define BB 32
#define UU 64
#define FF 66
#define MM 5
#define XHC 2048       // xh row elements (4096 B)
#define XIC 64         // xi row elements (128 B)
#define CAP 128        // max nnz/row (mean ~41), multiple of 16
#define KPAD 360       // lx row stride in bf16 (720 B)
#define KSTEPS 11      // 11*32 = 352 >= 330
#define WF_G (8*11*64*8)   // 45056 gate W-frag elements
#define WF_C (4*11*64*8)   // 22528 cand W-frag elements

typedef unsigned short u16;
typedef __attribute__((ext_vector_type(8))) short short8;
typedef __attribute__((ext_vector_type(4))) float float4v;

__device__ __forceinline__ u16 f2bf(float f) {
  unsigned u = __float_as_uint(f);
  u += 0x7FFFu + ((u >> 16) & 1u);   // RNE
  return (u16)(u >> 16);
}
__device__ __forceinline__ unsigned pack2(float lo, float hi) {
  return (unsigned)f2bf(lo) | ((unsigned)f2bf(hi) << 16);
}
__device__ __forceinline__ float bflo(unsigned d) { return __uint_as_float(d << 16); }
__device__ __forceinline__ float bfhi(unsigned d) { return __uint_as_float(d & 0xFFFF0000u); }

__device__ __forceinline__ float sigmoidf_(float x) {
  return 1.0f / (1.0f + __expf(-x));
}
__device__ __forceinline__ float tanhf_(float x) {
  x = fminf(fmaxf(x, -15.f), 15.f);
  float e = __expf(2.f * x);
  return (e - 1.f) / (e + 1.f);
}

// ---------------- CSR extraction: one wave per row; rows zero-padded to %16 -
__global__ __launch_bounds__(256) void extract_csr(
    const float* __restrict__ S0, const float* __restrict__ S1,
    int* __restrict__ cols, float* __restrict__ vals, int* __restrict__ nnz) {
  int wave = threadIdx.x >> 6;
  int lane = threadIdx.x & 63;
  int row  = blockIdx.x * 4 + wave;
  int sup  = blockIdx.y;
  const float* srow = (sup ? S1 : S0) + (size_t)row * NN;
  int*   crow = cols + ((size_t)sup * NN + row) * CAP;
  float* vrow = vals + ((size_t)sup * NN + row) * CAP;
  int base = 0;
  for (int j0 = 0; j0 < NN; j0 += 64) {
    float v = srow[j0 + lane];
    unsigned long long mask = __ballot(v != 0.0f);
    if (v != 0.0f) {
      int pos = base + __popcll(mask & ((1ull << lane) - 1ull));
      if (pos < CAP) { crow[pos] = j0 + lane; vrow[pos] = v; }
    }
    base += __popcll(mask);
  }
  if (base > CAP) base = CAP;
  int padded = (base + 15) & ~15;
  if (padded > CAP) padded = CAP;
  int p = base + lane;
  if (p < padded) { crow[p] = 0; vrow[p] = 0.0f; }
  if (lane == 0) nnz[sup * NN + row] = padded;
}

// ---------------- weight prep: W -> MFMA B-fragment order --------------------
// Wf[(tile*11+ks)*64*8 + lane*8 + j] = W[k=ks*32+(lane>>4)*8+j][o=tile*16+(lane&15)]
__global__ __launch_bounds__(256) void prep_w(
    const float* __restrict__ W, const float* __restrict__ W2,
    u16* __restrict__ Wf, u16* __restrict__ W2f) {
  int idx = blockIdx.x * 256 + threadIdx.x;
  if (idx < WF_G) {
    int j = idx & 7, lane = (idx >> 3) & 63, q = idx >> 9;
    int ks = q % 11, t = q / 11;
    int k = ks * 32 + (lane >> 4) * 8 + j, o = t * 16 + (lane & 15);
    float v = 0.f;
    if (k < 330) { int m = k / FF, f = k - m * FF; v = W[((size_t)f * MM + m) * 128 + o]; }
    Wf[idx] = f2bf(v);
  } else if (idx < WF_G + WF_C) {
    int i2 = idx - WF_G;
    int j = i2 & 7, lane = (i2 >> 3) & 63, q = i2 >> 9;
    int ks = q % 11, t = q / 11;
    int k = ks * 32 + (lane >> 4) * 8 + j, o = t * 16 + (lane & 15);
    float v = 0.f;
    if (k < 330) { int m = k / FF, f = k - m * FF; v = W2[((size_t)f * MM + m) * UU + o]; }
    W2f[i2] = f2bf(v);
  }
}

// ---------------- build xi0 / xh0 -------------------------------------------
__global__ __launch_bounds__(256) void build_x0(
    const float* __restrict__ inp, const float* __restrict__ hx,
    u16* __restrict__ xi0, u16* __restrict__ xh0) {
  int n = blockIdx.x;
  unsigned* xhd = (unsigned*)(xh0 + (size_t)n * XHC);
  for (int j = threadIdx.x; j < XHC / 2; j += 256) {   // 1024 dwords
    int b = j >> 5, f2 = (j & 31) * 2;
    const float* h = hx + (size_t)b * (NN * UU) + (size_t)n * UU + f2;
    xhd[j] = pack2(h[0], h[1]);
  }
  if (threadIdx.x < 32) {
    int b = threadIdx.x;
    unsigned* xid = (unsigned*)(xi0 + (size_t)n * XIC);
    xid[b] = pack2(inp[(size_t)b * (NN * 2) + n * 2],
                   inp[(size_t)b * (NN * 2) + n * 2 + 1]);
  }
}

// ---------------- SpMM: 4 x 1 KB panels, wave-uniform nnz, 16-deep MLP ------
__device__ __forceinline__ void fma8(float v, uint4 q, float* a) {
  a[0] = fmaf(v, bflo(q.x), a[0]); a[1] = fmaf(v, bfhi(q.x), a[1]);
  a[2] = fmaf(v, bflo(q.y), a[2]); a[3] = fmaf(v, bfhi(q.y), a[3]);
  a[4] = fmaf(v, bflo(q.z), a[4]); a[5] = fmaf(v, bfhi(q.z), a[5]);
  a[6] = fmaf(v, bflo(q.w), a[6]); a[7] = fmaf(v, bfhi(q.w), a[7]);
}

__global__ __launch_bounds__(256, 3) void spmm_panel(
    const int* __restrict__ cols, const float* __restrict__ vals,
    const int* __restrict__ nnz,
    const u16* xiA, const u16* xhA, const u16* xiB, const u16* xhB,
    const u16* zi, const u16* zh,
    float alpha, float beta, int sup_base,
    u16* yiA, u16* yhA, u16* yiB, u16* yhB) {
  int panel = blockIdx.x & 3;          // 4 panels x 1024 B
  int lane  = threadIdx.x & 63;
  int wv    = threadIdx.x >> 6;
  int row   = (blockIdx.x >> 2) * 4 + wv;
  const u16* xi = blockIdx.y ? xiB : xiA;
  const u16* xh = blockIdx.y ? xhB : xhA;
  u16* yi = blockIdx.y ? yiB : yiA;
  u16* yh = blockIdx.y ? yhB : yhA;
  int srow = __builtin_amdgcn_readfirstlane((sup_base + blockIdx.y) * NN + row);
  const int*   crow = cols + (size_t)srow * CAP;
  const float* vrow = vals + (size_t)srow * CAP;
  int cnt = nnz[srow];                 // multiple of 16, vals zero-padded
  int panoff = panel * 512 + lane * 8; // elements within xh row
  bool doi = (panel == 0) && (lane < 32);
  float a[8] = {0.f,0.f,0.f,0.f,0.f,0.f,0.f,0.f};
  float ai0 = 0.f, ai1 = 0.f;

  for (int k0 = 0; k0 < cnt; k0 += 16) {
    int cc[16]; float vv[16];
#pragma unroll
    for (int i = 0; i < 16; ++i) { cc[i] = crow[k0 + i]; vv[i] = vrow[k0 + i]; }
    uint4 q[16];
#pragma unroll
    for (int i = 0; i < 16; ++i)
      q[i] = *(const uint4*)(xh + (size_t)cc[i] * XHC + panoff);
    unsigned qi[16];
    if (doi) {
#pragma unroll
      for (int i = 0; i < 16; ++i)
        qi[i] = *(const unsigned*)(xi + (size_t)cc[i] * XIC + lane * 2);
    }
#pragma unroll
    for (int i = 0; i < 16; ++i) {
      fma8(vv[i], q[i], a);
      if (doi) {
        ai0 = fmaf(vv[i], bflo(qi[i]), ai0);
        ai1 = fmaf(vv[i], bfhi(qi[i]), ai1);
      }
    }
  }

  u16* yrow = yh + (size_t)row * XHC + panoff;
  float r[8];
#pragma unroll
  for (int j = 0; j < 8; ++j) r[j] = alpha * a[j];
  if (zh) {
    uint4 zq = *(const uint4*)(zh + (size_t)row * XHC + panoff);
    r[0] += beta * bflo(zq.x); r[1] += beta * bfhi(zq.x);
    r[2] += beta * bflo(zq.y); r[3] += beta * bfhi(zq.y);
    r[4] += beta * bflo(zq.z); r[5] += beta * bfhi(zq.z);
    r[6] += beta * bflo(zq.w); r[7] += beta * bfhi(zq.w);
  }
  uint4 o4;
  o4.x = pack2(r[0], r[1]); o4.y = pack2(r[2], r[3]);
  o4.z = pack2(r[4], r[5]); o4.w = pack2(r[6], r[7]);
  *(uint4*)yrow = o4;
  if (doi) {
    float s0 = alpha * ai0, s1 = alpha * ai1;
    if (zi) {
      unsigned zq = *(const unsigned*)(zi + (size_t)row * XIC + lane * 2);
      s0 += beta * bflo(zq); s1 += beta * bfhi(zq);
    }
    *(unsigned*)(yi + (size_t)row * XIC + lane * 2) = pack2(s0, s1);
  }
}

// ---------------- staging: 5 (xi,xh) mats -> lx[b][k=m*66+f], pad zeroed ----
__device__ __forceinline__ void stage_one(
    unsigned* lxd, int n, int m, const u16* xim, const u16* xhm) {
  const unsigned* sh = (const unsigned*)(xhm + (size_t)n * XHC);
  for (int j = threadIdx.x; j < XHC / 2; j += 256) {    // 1024 dwords
    int b = j >> 5, f2d = j & 31;
    lxd[b * (KPAD / 2) + m * 33 + 1 + f2d] = sh[j];
  }
  if (threadIdx.x < 32) {
    const unsigned* si = (const unsigned*)(xim + (size_t)n * XIC);
    lxd[threadIdx.x * (KPAD / 2) + m * 33] = si[threadIdx.x];
  }
}
__device__ __forceinline__ void stage_mats(
    unsigned* lxd, int n,
    const u16* i0, const u16* i1, const u16* i2, const u16* i3, const u16* i4,
    const u16* h0, const u16* h1, const u16* h2, const u16* h3, const u16* h4) {
  stage_one(lxd, n, 0, i0, h0);
  stage_one(lxd, n, 1, i1, h1);
  stage_one(lxd, n, 2, i2, h2);
  stage_one(lxd, n, 3, i3, h3);
  stage_one(lxd, n, 4, i4, h4);
  for (int i = threadIdx.x; i < BB * 16; i += 256) {    // zero k in [330,360)
    int b = i >> 4, d = i & 15;
    if (d < 15) lxd[b * (KPAD / 2) + 165 + d] = 0u;
  }
}

// ---------------- gate: sigmoid(x@W+bias); r*hx -> xh' (in place), u->ubuf --
__global__ __launch_bounds__(256) void gate_mfma(
    const u16* i0, const u16* __restrict__ i1, const u16* __restrict__ i2,
    const u16* __restrict__ i3, const u16* __restrict__ i4,
    const u16* h0, const u16* __restrict__ h1, const u16* __restrict__ h2,
    const u16* __restrict__ h3, const u16* __restrict__ h4,
    const u16* __restrict__ Wf, const float* __restrict__ bias,
    const float* __restrict__ hx,
    u16* xhp, float* __restrict__ ubuf) {
  __shared__ u16 lx[BB * KPAD];
  __shared__ u16 lt[BB * UU];           // r*hx staging [b][o]
  int n = blockIdx.x;
  stage_mats((unsigned*)lx, n, i0, i1, i2, i3, i4, h0, h1, h2, h3, h4);
  __syncthreads();
  int lane = threadIdx.x & 63;
  int w = threadIdx.x >> 6;
  int Mtile = w & 1;
  int Nbase = (w >> 1) * 4;             // waves 0,1 -> o 0..63; waves 2,3 -> 64..127
  int colo = lane & 15;
  int quad = lane >> 4;
  float4v acc[4];
#pragma unroll
  for (int t = 0; t < 4; ++t) {
    float bv = bias[(Nbase + t) * 16 + colo];
    acc[t] = (float4v){bv, bv, bv, bv};
  }
  const u16* arow = &lx[(Mtile * 16 + colo) * KPAD];
  for (int ks = 0; ks < KSTEPS; ++ks) {
    short8 af = *(const short8*)(arow + ks * 32 + quad * 8);
#pragma unroll
    for (int t = 0; t < 4; ++t) {
      short8 bf = *(const short8*)(Wf + (size_t)(((Nbase + t) * KSTEPS + ks) * 64 + lane) * 8);
      acc[t] = __builtin_amdgcn_mfma_f32_16x16x32_bf16(af, bf, acc[t], 0, 0, 0);
    }
  }
  int brow0 = Mtile * 16 + quad * 4;
#pragma unroll
  for (int t = 0; t < 4; ++t) {
    int o = (Nbase + t) * 16 + colo;
#pragma unroll
    for (int r = 0; r < 4; ++r) {
      int b = brow0 + r;
      float s = sigmoidf_(acc[t][r]);
      if (o < UU) {
        float h = hx[(size_t)b * (NN * UU) + (size_t)n * UU + o];
        lt[b * UU + o] = f2bf(s * h);
      } else {
        ubuf[(size_t)n * (BB * UU) + b * UU + (o - UU)] = s;
      }
    }
  }
  __syncthreads();
  unsigned* xrow = (unsigned*)(xhp + (size_t)n * XHC);
  const unsigned* ltd = (const unsigned*)lt;
  for (int j = threadIdx.x; j < XHC / 2; j += 256)
    xrow[j] = ltd[j];
}

// ---------------- candidate + final combine ---------------------------------
__global__ __launch_bounds__(256) void cand_mfma(
    const u16* __restrict__ i0, const u16* __restrict__ i1,
    const u16* __restrict__ i2, const u16* __restrict__ i3,
    const u16* __restrict__ i4,
    const u16* __restrict__ h0, const u16* __restrict__ h1,
    const u16* __restrict__ h2, const u16* __restrict__ h3,
    const u16* __restrict__ h4,
    const u16* __restrict__ W2f, const float* __restrict__ b2,
    const float* __restrict__ hx, const float* __restrict__ ubuf,
    float* __restrict__ out) {
  __shared__ u16 lx[BB * KPAD];
  int n = blockIdx.x;
  stage_mats((unsigned*)lx, n, i0, i1, i2, i3, i4, h0, h1, h2, h3, h4);
  __syncthreads();
  int lane = threadIdx.x & 63;
  int w = threadIdx.x >> 6;
  int Mtile = w & 1;
  int Nbase = (w >> 1) * 2;             // o 0..63 over 4 N-tiles
  int colo = lane & 15;
  int quad = lane >> 4;
  float4v acc[2];
#pragma unroll
  for (int t = 0; t < 2; ++t) {
    float bv = b2[(Nbase + t) * 16 + colo];
    acc[t] = (float4v){bv, bv, bv, bv};
  }
  const u16* arow = &lx[(Mtile * 16 + colo) * KPAD];
  for (int ks = 0; ks < KSTEPS; ++ks) {
    short8 af = *(const short8*)(arow + ks * 32 + quad * 8);
#pragma unroll
    for (int t = 0; t < 2; ++t) {
      short8 bf = *(const short8*)(W2f + (size_t)(((Nbase + t) * KSTEPS + ks) * 64 + lane) * 8);
      acc[t] = __builtin_amdgcn_mfma_f32_16x16x32_bf16(af, bf, acc[t], 0, 0, 0);
    }
  }
  int brow0 = Mtile * 16 + quad * 4;
#pragma unroll
  for (int t = 0; t < 2; ++t) {
    int o = (Nbase + t) * 16 + colo;
#pragma unroll
    for (int r = 0; r < 4; ++r) {
      int b = brow0 + r;
      float c = tanhf_(acc[t][r]);
      float u = ubuf[(size_t)n * (BB * UU) + b * UU + o];
      float h = hx[(size_t)b * (NN * UU) + (size_t)n * UU + o];
      out[(size_t)b * (NN * UU) + (size_t)n * UU + o] = u * h + (1.0f - u) * c;
    }
  }
}

extern "C" void kernel_launch(void* const* d_in, const int* in_sizes, int n_in,
                              void* d_out, int out_size, void* d_ws, size_t ws_size,
                              hipStream_t stream) {
  const float* inp  = (const float*)d_in[0];
  const float* hx   = (const float*)d_in[1];
  const float* S0   = (const float*)d_in[2];
  const float* S1   = (const float*)d_in[3];
  const float* W    = (const float*)d_in[4];
  const float* bias = (const float*)d_in[5];
  const float* W2   = (const float*)d_in[6];
  const float* b2   = (const float*)d_in[7];
  float* out = (float*)d_out;

  char* ws = (char*)d_ws;
  const size_t XHB = (size_t)NN * XHC * sizeof(u16);   // 16,777,216 B
  const size_t XIB = (size_t)NN * XIC * sizeof(u16);   // 524,288 B
  u16* bufA = (u16*)(ws);              // xh0 -> xh'
  u16* bufB = (u16*)(ws + 1 * XHB);    // S0@x  (h)
  u16* bufC = (u16*)(ws + 2 * XHB);    // cheb0 (h)
  u16* bufD = (u16*)(ws + 3 * XHB);    // S1@x  (h)
  u16* bufE = (u16*)(ws + 4 * XHB);    // cheb1 (h)
  char* p = ws + 5 * XHB;
  u16* xi0 = (u16*)p;  p += XIB;
  u16* yi1 = (u16*)p;  p += XIB;
  u16* yi2 = (u16*)p;  p += XIB;
  u16* yi3 = (u16*)p;  p += XIB;
  u16* yi4 = (u16*)p;  p += XIB;
  float* ubuf = (float*)p;             p += (size_t)NN * BB * UU * 4;
  int*   cols = (int*)p;               p += 2 * (size_t)NN * CAP * 4;
  float* vals = (float*)p;             p += 2 * (size_t)NN * CAP * 4;
  int*   nnzA = (int*)p;               p += 2 * (size_t)NN * 4;
  u16*   Wf   = (u16*)p;               p += (size_t)WF_G * 2;
  u16*   W2f  = (u16*)p;

  prep_w<<<(WF_G + WF_C + 255) / 256, 256, 0, stream>>>(W, W2, Wf, W2f);
  extract_csr<<<dim3(NN / 4, 2), 256, 0, stream>>>(S0, S1, cols, vals, nnzA);
  build_x0<<<NN, 256, 0, stream>>>(inp, hx, xi0, bufA);

  // gconv1: hop1 pair, then cheb pair (y selects support AND source)
  spmm_panel<<<dim3(4096, 2), 256, 0, stream>>>(cols, vals, nnzA,
      xi0, bufA, xi0, bufA, nullptr, nullptr, 1.f, 0.f, 0,
      yi1, bufB, yi3, bufD);
  spmm_panel<<<dim3(4096, 2), 256, 0, stream>>>(cols, vals, nnzA,
      yi1, bufB, yi3, bufD, xi0, bufA, 2.f, -1.f, 0,
      yi2, bufC, yi4, bufE);

  // gate: writes xh' in place into bufA, u -> ubuf
  gate_mfma<<<NN, 256, 0, stream>>>(xi0, yi1, yi2, yi3, yi4,
                                    bufA, bufB, bufC, bufD, bufE,
                                    Wf, bias, hx, bufA, ubuf);

  // gconv2 on x0' = (xi0, bufA)
  spmm_panel<<<dim3(4096, 2), 256, 0, stream>>>(cols, vals, nnzA,
      xi0, bufA, xi0, bufA, nullptr, nullptr, 1.f, 0.f, 0,
      yi1, bufB, yi3, bufD);
  spmm_panel<<<dim3(4096, 2), 256, 0, stream>>>(cols, vals, nnzA,
      yi1, bufB, yi3, bufD, xi0, bufA, 2.f, -1.f, 0,
      yi2, bufC, yi4, bufE);

  // candidate + final combine
  cand_mfma<<<NN, 256, 0, stream>>>(xi0, yi1, yi2, yi3, yi4,
                                    bufA, bufB, bufC, bufD, bufE,
                                    W2f, b2, hx, ubuf, out);
}